// Round 1
// baseline (78.788 us; speedup 1.0000x reference)
//
#include <hip/hip_runtime.h>
#include <hip/hip_bf16.h>

// 4-qubit QNN: encoding RY(x) per sample + fixed variational block (shared
// weights) + <Z_q> readout.  The variational block is a constant 16x16
// unitary U; <Z_q> = s0^T Re(U^+ Z_q U) s0 with s0 a product state in
// v(t)=[cos(t/2),sin(t/2)].  This collapses each output to a 5x5 bilinear
// form in the degree-4 monomials of (c0,s0) and (c1,s1):
//   out_q = sum_{m,n} C[q][m][n] * c0^{4-m} s0^m * c1^{4-n} s1^n
// Setup kernel (1 block) builds U from the 36 weights and reduces to
// C[4][5][5] = 100 floats in d_ws; batch kernel is then pure streaming:
// 8 B in, ~135 VALU, 16 B out per sample.  Memory-bound at ~24 MB total.

__global__ __launch_bounds__(256) void qnn_setup(const float* __restrict__ w,
                                                 float* __restrict__ C_out) {
    __shared__ float Ur[16][16];
    __shared__ float Ui[16][16];
    __shared__ float Csh[100];
    const int t = threadIdx.x;

    if (t < 100) Csh[t] = 0.0f;

    if (t < 16) {
        // Thread t owns column t of U (a state vector); left-multiplying U by
        // a gate applies the gate independently to each column.
        float ar[16], ai[16];
#pragma unroll
        for (int i = 0; i < 16; i++) { ar[i] = (i == t) ? 1.0f : 0.0f; ai[i] = 0.0f; }

#pragma unroll
        for (int l = 0; l < 3; l++) {
#pragma unroll
            for (int wq = 0; wq < 4; wq++) {
                const int st = 1 << (3 - wq);   // wire wq lives at bit (3-wq)
                float th, s, c;
                // RX(w[l][wq][0]):  a' = c*a - i s*b ; b' = -i s*a + c*b
                th = w[(l * 4 + wq) * 3 + 0] * 0.5f;
                __sincosf(th, &s, &c);
#pragma unroll
                for (int lo = 0; lo < 16; lo++) if (!(lo & st)) {
                    const int hi = lo | st;
                    const float arl = ar[lo], ail = ai[lo], arh = ar[hi], aih = ai[hi];
                    ar[lo] = c * arl + s * aih;
                    ai[lo] = c * ail - s * arh;
                    ar[hi] = c * arh + s * ail;
                    ai[hi] = c * aih - s * arl;
                }
                // RY(w[l][wq][1]):  a' = c*a - s*b ; b' = s*a + c*b (real)
                th = w[(l * 4 + wq) * 3 + 1] * 0.5f;
                __sincosf(th, &s, &c);
#pragma unroll
                for (int lo = 0; lo < 16; lo++) if (!(lo & st)) {
                    const int hi = lo | st;
                    const float arl = ar[lo], ail = ai[lo], arh = ar[hi], aih = ai[hi];
                    ar[lo] = c * arl - s * arh;
                    ai[lo] = c * ail - s * aih;
                    ar[hi] = s * arl + c * arh;
                    ai[hi] = s * ail + c * aih;
                }
                // RZ(w[l][wq][2]):  a' = (c - i s)*a ; b' = (c + i s)*b
                th = w[(l * 4 + wq) * 3 + 2] * 0.5f;
                __sincosf(th, &s, &c);
#pragma unroll
                for (int lo = 0; lo < 16; lo++) if (!(lo & st)) {
                    const int hi = lo | st;
                    const float arl = ar[lo], ail = ai[lo], arh = ar[hi], aih = ai[hi];
                    ar[lo] = c * arl + s * ail;
                    ai[lo] = c * ail - s * arl;
                    ar[hi] = c * arh - s * aih;
                    ai[hi] = c * aih + s * arh;
                }
            }
            // CNOT(i, (i+1)%4), i = 0..3, applied sequentially
#pragma unroll
            for (int ci = 0; ci < 4; ci++) {
                const int cst = 1 << (3 - ci);
                const int tst = 1 << (3 - ((ci + 1) & 3));
#pragma unroll
                for (int k = 0; k < 16; k++) if ((k & cst) && !(k & tst)) {
                    const int k2 = k | tst;
                    const float tr = ar[k], ti = ai[k];
                    ar[k] = ar[k2]; ai[k] = ai[k2];
                    ar[k2] = tr;    ai[k2] = ti;
                }
            }
        }
#pragma unroll
        for (int i = 0; i < 16; i++) { Ur[i][t] = ar[i]; Ui[i][t] = ai[i]; }
    }
    __syncthreads();

    // Thread t = i*16+j computes M_q[i][j] = Re(sum_k conj(U[k][i]) z_q(k) U[k][j])
    // and folds it into C[q][m][n] where m = popcount of x0-wire bits of (i,j),
    // n = popcount of x1-wire bits.  Wires 0,2 (bits 3,1) carry x0; wires 1,3
    // (bits 2,0) carry x1.
    {
        const int i = t >> 4;
        const int j = t & 15;
        float m0 = 0.f, m1 = 0.f, m2 = 0.f, m3 = 0.f;
#pragma unroll
        for (int k = 0; k < 16; k++) {
            const float r = Ur[k][i] * Ur[k][j] + Ui[k][i] * Ui[k][j];
            m0 += ((k >> 3) & 1) ? -r : r;
            m1 += ((k >> 2) & 1) ? -r : r;
            m2 += ((k >> 1) & 1) ? -r : r;
            m3 += ((k >> 0) & 1) ? -r : r;
        }
        const int mm = ((i >> 3) & 1) + ((i >> 1) & 1) + ((j >> 3) & 1) + ((j >> 1) & 1);
        const int nn = ((i >> 2) & 1) + (i & 1) + ((j >> 2) & 1) + (j & 1);
        atomicAdd(&Csh[0 * 25 + mm * 5 + nn], m0);
        atomicAdd(&Csh[1 * 25 + mm * 5 + nn], m1);
        atomicAdd(&Csh[2 * 25 + mm * 5 + nn], m2);
        atomicAdd(&Csh[3 * 25 + mm * 5 + nn], m3);
    }
    __syncthreads();
    if (t < 100) C_out[t] = Csh[t];
}

constexpr int SPT = 8;  // samples per thread

__global__ __launch_bounds__(256) void qnn_batch(const float2* __restrict__ x,
                                                 const float* __restrict__ C,
                                                 float4* __restrict__ out,
                                                 int B) {
    // Wave-uniform coefficient load, amortized over SPT samples/thread.
    float cf[100];
#pragma unroll
    for (int i = 0; i < 100; i++) cf[i] = C[i];

    const int base = blockIdx.x * (256 * SPT) + threadIdx.x;
#pragma unroll
    for (int k = 0; k < SPT; k++) {
        const int b = base + k * 256;
        if (b < B) {
            const float2 xv = x[b];
            float s0, c0, s1, c1;
            __sincosf(xv.x * 0.5f, &s0, &c0);
            __sincosf(xv.y * 0.5f, &s1, &c1);
            const float cc0 = c0 * c0, ss0 = s0 * s0, cs0 = c0 * s0;
            const float cc1 = c1 * c1, ss1 = s1 * s1, cs1 = c1 * s1;
            float p0[5] = { cc0 * cc0, cc0 * cs0, cs0 * cs0, cs0 * ss0, ss0 * ss0 };
            float p1[5] = { cc1 * cc1, cc1 * cs1, cs1 * cs1, cs1 * ss1, ss1 * ss1 };
            float o[4];
#pragma unroll
            for (int q = 0; q < 4; q++) {
                float acc = 0.0f;
#pragma unroll
                for (int m = 0; m < 5; m++) {
                    float inner = 0.0f;
#pragma unroll
                    for (int n = 0; n < 5; n++)
                        inner = fmaf(cf[q * 25 + m * 5 + n], p1[n], inner);
                    acc = fmaf(p0[m], inner, acc);
                }
                o[q] = acc;
            }
            out[b] = make_float4(o[0], o[1], o[2], o[3]);
        }
    }
}

extern "C" void kernel_launch(void* const* d_in, const int* in_sizes, int n_in,
                              void* d_out, int out_size, void* d_ws, size_t ws_size,
                              hipStream_t stream) {
    const float* x = (const float*)d_in[0];      // (B, 2) float32
    const float* w = (const float*)d_in[1];      // (3, 4, 3) float32
    float* C = (float*)d_ws;                     // 100 floats scratch
    const int B = in_sizes[0] / 2;

    qnn_setup<<<1, 256, 0, stream>>>(w, C);

    const int grid = (B + 256 * SPT - 1) / (256 * SPT);
    qnn_batch<<<grid, 256, 0, stream>>>((const float2*)x, C, (float4*)d_out, B);
}